// Round 5
// baseline (126.217 us; speedup 1.0000x reference)
//
#include <hip/hip_runtime.h>

#define HH 224
#define WW 224
#define PSD 112
#define NP 12544      // 112*112 patches per plane
#define NBG 1024      // B*G
#define NCH 28        // 4-patch chunks per patch row
#define PB 16         // patch rows per band
#define NBAND 7       // 7*16 = 112 patch rows
#define BROWS 33      // image rows per band (2*PB+1), bands overlap by 1 row
#define LSTRIDE 228   // words per LDS row: [0..2]=unused, [3]=left-pad(0), [4..227]=x cols 0..223
#define BQ (BROWS * WW / 4)   // 1848 float4 per band staging

// Stage image rows [32b-1, 32b+31] of plane xp into LDS band buffer.
// LDS col 4+c <-> x col c ; col 3 = zero pad (x col -1); row r<0 zero-filled.
__device__ __forceinline__ void stage_band(const float* __restrict__ xp,
                                           float* __restrict__ band,
                                           int b, int tid) {
    const int r0 = 32 * b - 1;
    for (int q = tid; q < BQ; q += 256) {
        const int rl = q / 56;                 // 56 float4 per row
        const int c = (q - rl * 56) * 4;
        const int r = r0 + rl;
        float4 v = make_float4(0.f, 0.f, 0.f, 0.f);
        if (r >= 0) v = *reinterpret_cast<const float4*>(xp + r * WW + c);
        *reinterpret_cast<float4*>(band + rl * LSTRIDE + 4 + c) = v;  // 16B aligned
    }
    for (int i = tid; i < BROWS; i += 256) band[i * LSTRIDE + 3] = 0.f;
}

// Read 9 consecutive LDS words (x cols 8t-1 .. 8t+7) for one image row.
__device__ __forceinline__ void lds_row9(const float* __restrict__ rp, float* L) {
    L[0] = rp[3];                                              // ds_read_b32
    float4 a = *reinterpret_cast<const float4*>(rp + 4);       // ds_read_b128 (16B aligned)
    float4 b = *reinterpret_cast<const float4*>(rp + 8);       // ds_read_b128
    L[1] = a.x; L[2] = a.y; L[3] = a.z; L[4] = a.w;
    L[5] = b.x; L[6] = b.y; L[7] = b.z; L[8] = b.w;
}

__global__ void __launch_bounds__(256) __attribute__((amdgpu_waves_per_eu(4, 4)))
scann_k(const float* __restrict__ x,
        const float* __restrict__ Wq, const float* __restrict__ bq,
        const float* __restrict__ Wk, const float* __restrict__ bk,
        const float* __restrict__ Wv, const float* __restrict__ bv,
        const float* __restrict__ Wo, const float* __restrict__ bo,
        float* __restrict__ out) {
    const int bg = blockIdx.x;
    const int g = bg & 63;
    const float* __restrict__ xp = x + (size_t)bg * (HH * WW);
    const int tid = threadIdx.x;

    __shared__ __align__(16) float band[BROWS * LSTRIDE];  // 30096 B
    __shared__ float red[4][56];
    __shared__ float sh[54];
    __shared__ float TT[81];
    __shared__ float Qm_s[9];
    __shared__ float wsh[81];
    __shared__ float cf[10];

    // ---------------- Phase 1: gram over 7 LDS-staged bands ----------------
    float acc[45];
    float sm[9];
#pragma unroll
    for (int k = 0; k < 45; ++k) acc[k] = 0.f;
#pragma unroll
    for (int i = 0; i < 9; ++i) sm[i] = 0.f;

    for (int b = 0; b < NBAND; ++b) {
        stage_band(xp, band, b, tid);
        __syncthreads();
        for (int task = tid; task < PB * NCH; task += 256) {
            const int phh = task / NCH;        // 0..15
            const int t = task - phh * NCH;    // 0..27
            const float* rowp = band + (2 * phh) * LSTRIDE + 8 * t;
            float L[3][9];
#pragma unroll
            for (int kr = 0; kr < 3; ++kr) lds_row9(rowp + kr * LSTRIDE, L[kr]);
#pragma unroll
            for (int u = 0; u < 4; ++u) {
                float v[9];
#pragma unroll
                for (int kh = 0; kh < 3; ++kh)
#pragma unroll
                    for (int kw = 0; kw < 3; ++kw) v[3 * kh + kw] = L[kh][2 * u + kw];
                int k = 0;
#pragma unroll
                for (int i = 0; i < 9; ++i) {
                    sm[i] += v[i];
#pragma unroll
                    for (int j = i; j < 9; ++j) {
                        acc[k] += v[i] * v[j];
                        ++k;
                    }
                }
            }
        }
        __syncthreads();
    }

    // ---------------- Phase 2: block reduction ----------------
    {
        const int lane = tid & 63;
        const int wv = tid >> 6;
#pragma unroll
        for (int k = 0; k < 45; ++k) {
            float v = acc[k];
#pragma unroll
            for (int off = 32; off; off >>= 1) v += __shfl_down(v, off, 64);
            if (lane == 0) red[wv][k] = v;
        }
#pragma unroll
        for (int i = 0; i < 9; ++i) {
            float v = sm[i];
#pragma unroll
            for (int off = 32; off; off >>= 1) v += __shfl_down(v, off, 64);
            if (lane == 0) red[wv][45 + i] = v;
        }
    }
    __syncthreads();
    if (tid < 54)
        sh[tid] = red[0][tid] + red[1][tid] + red[2][tid] + red[3][tid];
    __syncthreads();

    // ---------------- Phase 3: attention-weight solve (9 threads) ----------
#define MIDX(i, j) (9 * (i) - (i) * ((i)-1) / 2 + ((j) - (i)))
#define MAT(i, j) ((i) <= (j) ? sh[MIDX(i, j)] : sh[MIDX(j, i)])
    if (tid < 9) {
        const int t = tid;
        const float* wqt = Wq + g * 81 + t * 9;
        float w[9];
#pragma unroll
        for (int j = 0; j < 9; ++j) w[j] = wqt[j];
        float q = 0.f;
#pragma unroll
        for (int j = 0; j < 9; ++j) q += w[j] * sh[45 + j];
        Qm_s[t] = q;
#pragma unroll
        for (int i = 0; i < 9; ++i) {
            float s = 0.f;
#pragma unroll
            for (int j = 0; j < 9; ++j) s += MAT(i, j) * w[j];
            TT[i * 9 + t] = s;
        }
    }
    __syncthreads();
    if (tid < 9) {
        const int s = tid;
        const float* wks = Wk + g * 81 + s * 9;
        float w[9];
#pragma unroll
        for (int i = 0; i < 9; ++i) w[i] = wks[i];
        float Km = 0.f;
#pragma unroll
        for (int i = 0; i < 9; ++i) Km += w[i] * sh[45 + i];
        const float bks = bk[g * 9 + s];
        float e[9];
#pragma unroll
        for (int t = 0; t < 9; ++t) {
            const float bqt = bq[g * 9 + t];
            float sum = bks * Qm_s[t] + bqt * Km + 12544.f * bks * bqt;
#pragma unroll
            for (int i = 0; i < 9; ++i) sum += w[i] * TT[i * 9 + t];
            e[t] = sum;
        }
        float mx = e[0];
#pragma unroll
        for (int t = 1; t < 9; ++t) mx = fmaxf(mx, e[t]);
        float ex[9], se = 0.f;
#pragma unroll
        for (int t = 0; t < 9; ++t) {
            ex[t] = expf(e[t] - mx);
            se += ex[t];
        }
        const float wos = Wo[g * 9 + s] / se;
#pragma unroll
        for (int t = 0; t < 9; ++t) wsh[s * 9 + t] = wos * ex[t];
    }
    __syncthreads();
    if (tid < 9) {
        const int j = tid;
        float weff[9];
#pragma unroll
        for (int t = 0; t < 9; ++t) {
            float s = 0.f;
#pragma unroll
            for (int s2 = 0; s2 < 9; ++s2) s += wsh[s2 * 9 + t];
            weff[t] = s;
        }
        float cj = 0.f;
#pragma unroll
        for (int t = 0; t < 9; ++t) cj += weff[t] * Wv[g * 81 + t * 9 + j];
        cf[j] = cj;
        if (j == 0) {
            float d = bo[g];
#pragma unroll
            for (int t = 0; t < 9; ++t) d += weff[t] * bv[g * 9 + t];
            cf[9] = d;
        }
    }
    __syncthreads();

    // ---------------- Phase 4: conv over the same 7 bands ----------------
    float cc[9];
#pragma unroll
    for (int j = 0; j < 9; ++j) cc[j] = cf[j];
    const float dd = cf[9];
    float* __restrict__ op = out + (size_t)bg * NP;

    for (int b = 0; b < NBAND; ++b) {
        stage_band(xp, band, b, tid);
        __syncthreads();
        for (int task = tid; task < PB * NCH; task += 256) {
            const int phh = task / NCH;
            const int t = task - phh * NCH;
            const int ph = b * PB + phh;
            const float* rowp = band + (2 * phh) * LSTRIDE + 8 * t;
            float L[3][9];
#pragma unroll
            for (int kr = 0; kr < 3; ++kr) lds_row9(rowp + kr * LSTRIDE, L[kr]);
            float o[4];
#pragma unroll
            for (int u = 0; u < 4; ++u) {
                float s = dd;
#pragma unroll
                for (int kh = 0; kh < 3; ++kh)
#pragma unroll
                    for (int kw = 0; kw < 3; ++kw)
                        s += cc[3 * kh + kw] * L[kh][2 * u + kw];
                o[u] = s;
            }
            *reinterpret_cast<float4*>(op + ph * PSD + 4 * t) =
                make_float4(o[0], o[1], o[2], o[3]);
        }
        __syncthreads();
    }
}

extern "C" void kernel_launch(void* const* d_in, const int* in_sizes, int n_in,
                              void* d_out, int out_size, void* d_ws, size_t ws_size,
                              hipStream_t stream) {
    const float* x = (const float*)d_in[0];
    const float* Wq = (const float*)d_in[1];
    const float* bq = (const float*)d_in[2];
    const float* Wk = (const float*)d_in[3];
    const float* bk = (const float*)d_in[4];
    const float* Wv = (const float*)d_in[5];
    const float* bv = (const float*)d_in[6];
    const float* Wo = (const float*)d_in[7];
    const float* bo = (const float*)d_in[8];
    float* out = (float*)d_out;

    scann_k<<<NBG, 256, 0, stream>>>(x, Wq, bq, Wk, bk, Wv, bv, Wo, bo, out);
}